// Round 14
// baseline (299.177 us; speedup 1.0000x reference)
//
#include <hip/hip_runtime.h>

typedef _Float16 f16;
typedef _Float16 f16x2 __attribute__((ext_vector_type(2)));
typedef _Float16 f16x4 __attribute__((ext_vector_type(4)));
typedef _Float16 f16x8 __attribute__((ext_vector_type(8)));
typedef float f32x4 __attribute__((ext_vector_type(4)));

static __device__ __forceinline__ f32x4 mfma16(f16x8 a, f16x8 b, f32x4 c) {
  return __builtin_amdgcn_mfma_f32_16x16x32_f16(a, b, c, 0, 0, 0);
}

// direct global->LDS, 16B per lane; LDS dest = wave-uniform base + lane*16
#define GL16(GP, LP)                                                         \
  __builtin_amdgcn_global_load_lds(                                          \
      (const __attribute__((address_space(1))) void*)(GP),                   \
      (__attribute__((address_space(3))) void*)(LP), 16, 0, 0)

// ---------------- single pack kernel ----------------
// blocks [0,12288): x + 4 weights, float4 -> f16x4 vectorized
// blocks [12288,13312): relK pad + relVT transpose-pad
__global__ void pack_all_kernel(const float4* __restrict__ x, const float4* __restrict__ wq,
                                const float4* __restrict__ wk, const float4* __restrict__ wv,
                                const float4* __restrict__ wo, const float* __restrict__ relk,
                                const float* __restrict__ relv, f16* __restrict__ xh,
                                f16* __restrict__ wqh, f16* __restrict__ wkh,
                                f16* __restrict__ wvh, f16* __restrict__ woh,
                                f16* __restrict__ relKh, f16* __restrict__ relVTh) {
  if (blockIdx.x < 12288) {
    int i = blockIdx.x * 256 + threadIdx.x;  // 3,145,728 float4 total
    const float4* s;
    f16* d;
    int off;
    if (i < 2097152) {
      s = x;
      d = xh;
      off = i;
    } else {
      int j = i - 2097152;
      int seg = j >> 18;
      off = j & 262143;
      s = seg == 0 ? wq : seg == 1 ? wk : seg == 2 ? wv : wo;
      d = seg == 0 ? wqh : seg == 1 ? wkh : seg == 2 ? wvh : woh;
    }
    float4 v = s[off];
    f16x4 o = {(f16)v.x, (f16)v.y, (f16)v.z, (f16)v.w};
    *(f16x4*)&d[off * 4] = o;
  } else {
    int idx = (blockIdx.x - 12288) * 256 + threadIdx.x;  // 262144
    if (idx < 131072) {
      relKh[idx] = (idx < 2047 * 64) ? (f16)relk[idx] : (f16)0.f;
    } else {
      int k = idx - 131072;
      int dd = k >> 11, p = k & 2047;
      relVTh[k] = (p < 2047) ? (f16)relv[p * 64 + dd] : (f16)0.f;
    }
  }
}

// ---- shared GEMM inner loop: C[i,j] = (sum_k A[i,k]*B[j,k] + bias)*oscale ----
// 128x128, 4 waves, 2 blocks/CU. 2-phase pipeline: double-buffered LDS, next
// tile's global_load_lds issued BEFORE compute, counted vmcnt(8) across the
// raw s_barrier. XOR-swizzled unpadded tiles.
template <int OUT_F32>
static __device__ __forceinline__ void gemm_body(
    const f16* __restrict__ A, const f16* __restrict__ B,
    const float* __restrict__ bias, void* __restrict__ Cout, long i0, long j0,
    int N, int Kd, float oscale, bool biasRow, f16* Al, f16* Bl) {
  const int tid = threadIdx.x;
  const int w = tid >> 6, lane = tid & 63;
  const int l15 = lane & 15, hi = lane >> 4;
  const int wr = (w >> 1) * 64, wc = (w & 1) * 64;
  const int sx = (l15 & 7) * 8;  // read-side XOR swizzle (f16 units)

  // staging source (per-lane, inverse-swizzled); each GL16 line = 32 rows
  const int row_in = lane >> 3, c_lds = lane & 7;
  const int cg8 = (c_lds ^ row_in) * 8;
  const f16* agl = A + (i0 + w * 8 + row_in) * Kd + cg8;
  const f16* bgl = B + (j0 + w * 8 + row_in) * Kd + cg8;
  const int lbase = (w * 8) * 64;

#define GSTAGE(BUF, K0)                                          \
  do {                                                           \
    f16* al = Al + (BUF) * 8192 + lbase;                         \
    f16* bl = Bl + (BUF) * 8192 + lbase;                         \
    GL16(agl + (K0), al);                                        \
    GL16(agl + 32l * Kd + (K0), al + 32 * 64);                   \
    GL16(agl + 64l * Kd + (K0), al + 64 * 64);                   \
    GL16(agl + 96l * Kd + (K0), al + 96 * 64);                   \
    GL16(bgl + (K0), bl);                                        \
    GL16(bgl + 32l * Kd + (K0), bl + 32 * 64);                   \
    GL16(bgl + 64l * Kd + (K0), bl + 64 * 64);                   \
    GL16(bgl + 96l * Kd + (K0), bl + 96 * 64);                   \
  } while (0)

  f32x4 acc[4][4];
#pragma unroll
  for (int a = 0; a < 4; a++)
#pragma unroll
    for (int b2 = 0; b2 < 4; b2++) acc[a][b2] = (f32x4){0.f, 0.f, 0.f, 0.f};

  GSTAGE(0, 0);
  int cur = 0;
  for (int k0 = 0; k0 < Kd; k0 += 64) {
    if (k0 + 64 < Kd) {
      GSTAGE(cur ^ 1, k0 + 64);  // prefetch next tile into other buffer
      asm volatile("s_waitcnt vmcnt(8)" ::: "memory");  // cur tile landed
    } else {
      asm volatile("s_waitcnt vmcnt(0)" ::: "memory");
    }
    __builtin_amdgcn_s_barrier();
    __builtin_amdgcn_sched_barrier(0);
    const f16* Ac = Al + cur * 8192;
    const f16* Bc = Bl + cur * 8192;
#pragma unroll
    for (int ks = 0; ks < 2; ks++) {
      f16x8 af[4], bf[4];
#pragma unroll
      for (int mb = 0; mb < 4; mb++)
        af[mb] = *(const f16x8*)&Ac[(wr + mb * 16 + l15) * 64 + ((ks * 32 + hi * 8) ^ sx)];
#pragma unroll
      for (int nb = 0; nb < 4; nb++)
        bf[nb] = *(const f16x8*)&Bc[(wc + nb * 16 + l15) * 64 + ((ks * 32 + hi * 8) ^ sx)];
#pragma unroll
      for (int mb = 0; mb < 4; mb++)
#pragma unroll
        for (int nb = 0; nb < 4; nb++) acc[mb][nb] = mfma16(af[mb], bf[nb], acc[mb][nb]);
    }
    asm volatile("s_waitcnt lgkmcnt(0)" ::: "memory");  // reads done before swap
    __builtin_amdgcn_s_barrier();
    cur ^= 1;
  }
#undef GSTAGE
#pragma unroll
  for (int mb = 0; mb < 4; mb++) {
#pragma unroll
    for (int nb = 0; nb < 4; nb++) {
      long row = i0 + wr + mb * 16 + hi * 4;
      long col = j0 + wc + nb * 16 + l15;
      float bc = biasRow ? 0.f : bias[col];
#pragma unroll
      for (int i = 0; i < 4; i++) {
        float v = acc[mb][nb][i] + (biasRow ? bias[row + i] : bc);
        v *= oscale;
        if (OUT_F32)
          ((float*)Cout)[(row + i) * N + col] = v;
        else
          ((f16*)Cout)[(row + i) * N + col] = (f16)v;
      }
    }
  }
}

// ---- merged input GEMMs: Q, K projections + V^T, one 1536-block launch ----
// blocks [0,1024): QK (z = flat&1): C = x @ Wq/Wk^T + b, [8192][1024]
// blocks [1024,1536): V^T = Wv @ x^T (+bv row-bias), [1024][8192]
__global__ __launch_bounds__(256, 2) void gemm_in3(
    const f16* __restrict__ xh, const f16* __restrict__ Wqh, const f16* __restrict__ Wkh,
    const f16* __restrict__ Wvh, const float* __restrict__ bq,
    const float* __restrict__ bk, const float* __restrict__ bv,
    f16* __restrict__ Qh, f16* __restrict__ Kh, f16* __restrict__ Vth) {
  __shared__ __align__(16) f16 Al[2 * 128 * 64];
  __shared__ __align__(16) f16 Bl[2 * 128 * 64];
  const int flat = blockIdx.x;
  const f16 *A, *B;
  const float* bias;
  f16* C;
  float osc;
  long i0, j0;
  int N;
  bool biasRow;
  if (flat < 1024) {
    int z = flat & 1;
    int t = flat >> 1;  // bx = t&7, by = t>>3
    A = xh;
    B = z ? Wkh : Wqh;
    C = z ? Kh : Qh;
    bias = z ? bk : bq;
    osc = z ? 0.125f : 1.0f;
    i0 = (long)(t >> 3) * 128;
    j0 = (long)(t & 7) * 128;
    N = 1024;
    biasRow = false;
  } else {
    int t = flat - 1024;  // bx = t&63, by = t>>6
    A = Wvh;
    B = xh;
    C = Vth;
    bias = bv;
    osc = 1.0f;
    i0 = (long)(t >> 6) * 128;
    j0 = (long)(t & 63) * 128;
    N = 8192;
    biasRow = true;
  }
  gemm_body<0>(A, B, bias, C, i0, j0, N, 1024, osc, biasRow, Al, Bl);
}

// ---- output GEMM: out = AO @ Wo^T + bo (f32 out) ----
__global__ __launch_bounds__(256, 2) void gemm_out(
    const f16* __restrict__ AOh, const f16* __restrict__ Woh,
    const float* __restrict__ bo, float* __restrict__ out) {
  __shared__ __align__(16) f16 Al[2 * 128 * 64];
  __shared__ __align__(16) f16 Bl[2 * 128 * 64];
  gemm_body<1>(AOh, Woh, bo, out, (long)blockIdx.y * 128, (long)blockIdx.x * 128,
               1024, 1024, 1.0f, false, Al, Bl);
}

// ---------------- fused relative-position flash attention ----------------
// BM=128 per block (4 waves x 32 rows). Staging via global_load_lds (16B)
// into XOR-chunk-swizzled unpadded tiles; split drain (K/RK first, vmcnt(8)).
// P buffers (padded, ds_write scatter) alias K+RK+gap.
// Diagonal gather: source-side chunk pre-select, pack g-pair, one bpermute
// serves both groups (16 bpermutes/iter).
// grid 1024 = 8 qtiles x 128 bh, XCD-swizzled. LDS 77,824 B -> 2 blocks/CU.
__global__ __launch_bounds__(256, 2) void attn_kernel(
    const f16* __restrict__ Qh, const f16* __restrict__ Kh,
    const f16* __restrict__ Vth, const f16* __restrict__ relKh,
    const f16* __restrict__ relVTh, f16* __restrict__ AO) {
  // unified LDS, 38,912 f16 = 77,824 B
  __shared__ __align__(16) f16 SH[38912];
  f16* const ldsK = SH;            // [64][64]   staging
  f16* const ldsRK = SH + 4096;    // [192][64]  staging
  f16* const ldsP = SH;            // [128][72]  alias: Pmain (after B2)
  f16* const ldsPS = SH + 9216;    // [128][104] alias+gap: Pskew (after B2)
  f16* const ldsV = SH + 22528;    // [64][64]
  f16* const ldsRV = SH + 26624;   // [64][192]

  const int tid = threadIdx.x;
  const int w = tid >> 6, lane = tid & 63;
  const int l15 = lane & 15, hi = lane >> 4;
  // XCD swizzle: 8 q-tiles of one (b,h) consecutive on one XCD
  const int flat = blockIdx.x;
  const int xcd = flat & 7, slot = flat >> 3;
  const int bh = xcd * 16 + (slot >> 3);
  const int qt = slot & 7;
  const int b = bh >> 4, h = bh & 15;
  const int l0 = qt * 128;
  const int cu = 6 - 2 * w;      // RK union chunk base (6 chunks)
  const int rvco = 96 - 32 * w;  // PV-rel B-col base in RV band
  const int sx = (l15 & 7) * 8;  // read-side XOR swizzle (f16 units)

  // ---- global_load_lds source pointers (per-lane, inverse-swizzled) ----
  const int row_in = lane >> 3;   // 0..7
  const int c_lds = lane & 7;
  const int cg8 = (c_lds ^ row_in) * 8;
  const f16* kgl = Kh + ((long)(b * 1024 + w * 16 + row_in)) * 1024 + h * 64 + cg8;
  const f16* vgl = Vth + ((long)(h * 64 + w * 16 + row_in)) * 8192 + b * 1024 + cg8;
  const f16* rkgl = relKh + (long)(896 - l0 + w * 48 + row_in) * 64 + cg8;
  // RV flat: issue q covers flat 16B-chunks f = (w*6+q)*64 + lane;
  // row = f/24, c = f%24, source chunk = c ^ (row&7)
#define RVP(Q)                                                                   \
  (relVTh + (long)(((w * 6 + (Q)) * 64 + lane) / 24) * 2048 + (896 - l0) +       \
   ((((w * 6 + (Q)) * 64 + lane) % 24) ^ ((((w * 6 + (Q)) * 64 + lane) / 24) & 7)) * 8)
  const f16* rvg0 = RVP(0);
  const f16* rvg1 = RVP(1);
  const f16* rvg2 = RVP(2);
  const f16* rvg3 = RVP(3);
  const f16* rvg4 = RVP(4);
  const f16* rvg5 = RVP(5);
#undef RVP

  // Q fragments: rows l0 + 32w + 16g + l15, k-halves ks
  const long qbase = ((long)(b * 1024 + l0 + w * 32 + l15)) * 1024 + h * 64 + hi * 8;
  const f16x8 qf00 = *(const f16x8*)(Qh + qbase);
  const f16x8 qf01 = *(const f16x8*)(Qh + qbase + 32);
  const f16x8 qf10 = *(const f16x8*)(Qh + qbase + 16l * 1024);
  const f16x8 qf11 = *(const f16x8*)(Qh + qbase + 16l * 1024 + 32);

  const f16x8 ones1 = {(f16)1.f, (f16)1.f, (f16)1.f, (f16)1.f,
                       (f16)1.f, (f16)1.f, (f16)1.f, (f16)1.f};

  f32x4 acc_o[2][4];
#pragma unroll
  for (int g = 0; g < 2; g++)
#pragma unroll
    for (int cf = 0; cf < 4; cf++) acc_o[g][cf] = (f32x4){0.f, 0.f, 0.f, 0.f};
  float mrow[2][4], lsum[2][4];
#pragma unroll
  for (int g = 0; g < 2; g++)
#pragma unroll
    for (int i = 0; i < 4; i++) {
      mrow[g][i] = -1e30f;
      lsum[g][i] = 0.f;
    }

  for (int kt = 0; kt < 16; kt++) {
    const int r0 = kt * 64;
    __syncthreads();  // B0: all PV + P-alias reads of prev iter done
    {
      // K/RK first (8 lines) -- needed at B1 for QK
      const long ko = (long)r0 * 1024;
      GL16(kgl + ko, ldsK + (w * 16) * 64);
      GL16(kgl + ko + 8 * 1024, ldsK + (w * 16 + 8) * 64);
      const int rko = r0 * 64;
      GL16(rkgl + rko, ldsRK + (w * 48) * 64);
      GL16(rkgl + rko + 512, ldsRK + (w * 48 + 8) * 64);
      GL16(rkgl + rko + 1024, ldsRK + (w * 48 + 16) * 64);
      GL16(rkgl + rko + 1536, ldsRK + (w * 48 + 24) * 64);
      GL16(rkgl + rko + 2048, ldsRK + (w * 48 + 32) * 64);
      GL16(rkgl + rko + 2560, ldsRK + (w * 48 + 40) * 64);
      // V/RV last (8 lines) -- only needed by PV (guaranteed by B2 drain)
      GL16(vgl + r0, ldsV + (w * 16) * 64);
      GL16(vgl + r0 + 8l * 8192, ldsV + (w * 16 + 8) * 64);
      GL16(rvg0 + r0, ldsRV + (w * 6 + 0) * 512);
      GL16(rvg1 + r0, ldsRV + (w * 6 + 1) * 512);
      GL16(rvg2 + r0, ldsRV + (w * 6 + 2) * 512);
      GL16(rvg3 + r0, ldsRV + (w * 6 + 3) * 512);
      GL16(rvg4 + r0, ldsRV + (w * 6 + 4) * 512);
      GL16(rvg5 + r0, ldsRV + (w * 6 + 5) * 512);
    }
    // B1 split drain: wait only for own K/RK (first 8), barrier, pin order.
    asm volatile("s_waitcnt vmcnt(8)" ::: "memory");
    __builtin_amdgcn_s_barrier();
    __builtin_amdgcn_sched_barrier(0);

    // QK: S = Q*(K/8)^T per group; QR = Q·relK over 5 chunks/group
    f32x4 sacc[2][4], qracc[2][5];
#pragma unroll
    for (int g = 0; g < 2; g++) {
#pragma unroll
      for (int cf = 0; cf < 4; cf++) sacc[g][cf] = (f32x4){0.f, 0.f, 0.f, 0.f};
#pragma unroll
      for (int j = 0; j < 5; j++) qracc[g][j] = (f32x4){0.f, 0.f, 0.f, 0.f};
    }
    __builtin_amdgcn_s_setprio(1);
#pragma unroll
    for (int ks = 0; ks < 2; ks++) {
      f16x8 kf[4], rf[6];
#pragma unroll
      for (int cf = 0; cf < 4; cf++)
        kf[cf] = *(const f16x8*)&ldsK[(cf * 16 + l15) * 64 + ((ks * 32 + hi * 8) ^ sx)];
#pragma unroll
      for (int j = 0; j < 6; j++)
        rf[j] =
            *(const f16x8*)&ldsRK[((cu + j) * 16 + l15) * 64 + ((ks * 32 + hi * 8) ^ sx)];
      f16x8 q0 = ks ? qf01 : qf00;
      f16x8 q1 = ks ? qf11 : qf10;
#pragma unroll
      for (int cf = 0; cf < 4; cf++) {
        sacc[0][cf] = mfma16(q0, kf[cf], sacc[0][cf]);
        sacc[1][cf] = mfma16(q1, kf[cf], sacc[1][cf]);
      }
#pragma unroll
      for (int j = 0; j < 5; j++) {
        qracc[0][j] = mfma16(q0, rf[j + 1], qracc[0][j]);
        qracc[1][j] = mfma16(q1, rf[j], qracc[1][j]);
      }
    }
    __builtin_amdgcn_s_setprio(0);
    __syncthreads();  // B2: QK reads done (+full vmcnt drain: V/RV landed)

    // in-register diagonal gather, source-side pre-select:
    // src lane (pos p=l15 in its 16-lane group) serves exactly one consumer;
    // that consumer's wrap = (p + hi*4 + i <= 14). Pre-select chunk cf/cf+1
    // on the source, pack the g-pair, one bpermute serves both groups.
#pragma unroll
    for (int i = 0; i < 4; i++) {
      int t = 15 + l15 - (hi * 4 + i);
      int idx = (hi * 16 + (t & 15)) * 4;
      bool wrapc = (l15 + hi * 4 + i) <= 14;  // consumer-of-this-src wrap
#pragma unroll
      for (int cf = 0; cf < 4; cf++) {
        float s0 = wrapc ? qracc[0][cf + 1][i] : qracc[0][cf][i];
        float s1 = wrapc ? qracc[1][cf + 1][i] : qracc[1][cf][i];
        auto pkv = __builtin_amdgcn_cvt_pkrtz(s0, s1);
        int gg = __builtin_amdgcn_ds_bpermute(idx, __builtin_bit_cast(int, pkv));
        f16x2 two = __builtin_bit_cast(f16x2, gg);
        sacc[0][cf][i] += (float)two[0];
        sacc[1][cf][i] += (float)two[1];
      }
    }

    // online softmax per group
    float rmax[2][4];
#pragma unroll
    for (int g = 0; g < 2; g++)
#pragma unroll
      for (int i = 0; i < 4; i++)
        rmax[g][i] = fmaxf(fmaxf(sacc[g][0][i], sacc[g][1][i]),
                           fmaxf(sacc[g][2][i], sacc[g][3][i]));
#pragma unroll
    for (int m = 1; m < 16; m <<= 1)
#pragma unroll
      for (int g = 0; g < 2; g++)
#pragma unroll
        for (int i = 0; i < 4; i++)
          rmax[g][i] = fmaxf(rmax[g][i], __shfl_xor(rmax[g][i], m, 64));
    {
      bool big = false;
#pragma unroll
      for (int g = 0; g < 2; g++)
#pragma unroll
        for (int i = 0; i < 4; i++) big |= rmax[g][i] > mrow[g][i] + 8.f;
      if (__any(big)) {
#pragma unroll
        for (int g = 0; g < 2; g++)
#pragma unroll
          for (int i = 0; i < 4; i++) {
            float mn = fmaxf(mrow[g][i], rmax[g][i]);
            float al = __expf(mrow[g][i] - mn);
            mrow[g][i] = mn;
            lsum[g][i] *= al;
#pragma unroll
            for (int cf = 0; cf < 4; cf++) acc_o[g][cf][i] *= al;
          }
      }
    }
#pragma unroll
    for (int g = 0; g < 2; g++)
#pragma unroll
      for (int cf = 0; cf < 4; cf++)
#pragma unroll
        for (int i = 0; i < 4; i++)
          sacc[g][cf][i] = __expf(sacc[g][cf][i] - mrow[g][i]);  // P (<= e^8)

    // zero own PS rows' window [0,96), then scatter P
    const uint4 z4 = make_uint4(0u, 0u, 0u, 0u);
#pragma unroll
    for (int r2 = 0; r2 < 2; r2++)
#pragma unroll
      for (int s = 0; s < 3; s++)
        *(uint4*)&ldsPS[(w * 32 + r2 * 16 + (lane >> 2)) * 104 + (lane & 3) * 8 + 32 * s] =
            z4;
#pragma unroll
    for (int g = 0; g < 2; g++)
#pragma unroll
      for (int cf = 0; cf < 4; cf++)
#pragma unroll
        for (int i = 0; i < 4; i++) {
          int rr = 16 * g + hi * 4 + i;  // local row in wave [0,32)
          int ri = cf * 16 + l15;
          f16 ph = (f16)sacc[g][cf][i];
          ldsP[(w * 32 + rr) * 72 + ri] = ph;
          ldsPS[(w * 32 + rr) * 104 + 31 + ri - rr] = ph;  // col'' = 31+ri-rr
        }
    // DS pipe is in-order per wave: PV reads below see the scatter writes.
    __builtin_amdgcn_sched_barrier(0);

    __builtin_amdgcn_s_setprio(1);
    // O += P @ V ; row-sums via ones-MFMA on the same pa fragments
    f32x4 rs0 = (f32x4){0.f, 0.f, 0.f, 0.f}, rs1 = (f32x4){0.f, 0.f, 0.f, 0.f};
#pragma unroll
    for (int ks = 0; ks < 2; ks++) {
      f16x8 pa0 = *(const f16x8*)&ldsP[(w * 32 + l15) * 72 + ks * 32 + hi * 8];
      f16x8 pa1 = *(const f16x8*)&ldsP[(w * 32 + 16 + l15) * 72 + ks * 32 + hi * 8];
      rs0 = mfma16(pa0, ones1, rs0);
      rs1 = mfma16(pa1, ones1, rs1);
#pragma unroll
      for (int cf = 0; cf < 4; cf++) {
        f16x8 vb = *(const f16x8*)&ldsV[(cf * 16 + l15) * 64 + ((ks * 32 + hi * 8) ^ sx)];
        acc_o[0][cf] = mfma16(pa0, vb, acc_o[0][cf]);
        acc_o[1][cf] = mfma16(pa1, vb, acc_o[1][cf]);
      }
    }
    // O += Pskew @ relV_band (3 ks chunks, B-col base rvco = 96-32w)
#pragma unroll
    for (int ks = 0; ks < 3; ks++) {
      f16x8 ps0 = *(const f16x8*)&ldsPS[(w * 32 + l15) * 104 + ks * 32 + hi * 8];
      f16x8 ps1 = *(const f16x8*)&ldsPS[(w * 32 + 16 + l15) * 104 + ks * 32 + hi * 8];
#pragma unroll
      for (int cf = 0; cf < 4; cf++) {
        f16x8 rb = *(const f16x8*)&ldsRV[(cf * 16 + l15) * 192 +
                                         ((rvco + ks * 32 + hi * 8) ^ sx)];
        acc_o[0][cf] = mfma16(ps0, rb, acc_o[0][cf]);
        acc_o[1][cf] = mfma16(ps1, rb, acc_o[1][cf]);
      }
    }
    __builtin_amdgcn_s_setprio(0);
#pragma unroll
    for (int i = 0; i < 4; i++) {
      lsum[0][i] += rs0[i];
      lsum[1][i] += rs1[i];
    }
  }
  // epilogue: normalize, store fp16 to AO[b*1024+l][h*64+d]
#pragma unroll
  for (int g = 0; g < 2; g++)
#pragma unroll
    for (int cf = 0; cf < 4; cf++)
#pragma unroll
      for (int i = 0; i < 4; i++) {
        float v = acc_o[g][cf][i] / lsum[g][i];
        AO[((long)(b * 1024 + l0 + w * 32 + 16 * g + hi * 4 + i)) * 1024 + h * 64 +
           cf * 16 + l15] = (f16)v;
      }
}

// ---------------- launch ----------------
extern "C" void kernel_launch(void* const* d_in, const int* in_sizes, int n_in,
                              void* d_out, int out_size, void* d_ws, size_t ws_size,
                              hipStream_t stream) {
  const float* x = (const float*)d_in[0];
  const float* Wq = (const float*)d_in[1];
  const float* bq = (const float*)d_in[2];
  const float* Wk = (const float*)d_in[3];
  const float* bk = (const float*)d_in[4];
  const float* Wv = (const float*)d_in[5];
  const float* bv = (const float*)d_in[6];
  const float* Wo = (const float*)d_in[7];
  const float* bo = (const float*)d_in[8];
  const float* relk = (const float*)d_in[9];
  const float* relv = (const float*)d_in[10];
  float* out = (float*)d_out;

  char* ws = (char*)d_ws;
  size_t off = 0;
  auto alloc = [&](size_t bytes) {
    char* p = ws + off;
    off += (bytes + 255) & ~(size_t)255;
    return p;
  };
  f16* xh = (f16*)alloc(8192ull * 1024 * 2);
  f16* Wqh = (f16*)alloc(1024ull * 1024 * 2);
  f16* Wkh = (f16*)alloc(1024ull * 1024 * 2);
  f16* Wvh = (f16*)alloc(1024ull * 1024 * 2);
  f16* Woh = (f16*)alloc(1024ull * 1024 * 2);
  f16* relKh = (f16*)alloc(2048ull * 64 * 2);
  f16* relVTh = (f16*)alloc(64ull * 2048 * 2);
  f16* Qh = (f16*)alloc(8192ull * 1024 * 2);
  f16* Kh = (f16*)alloc(8192ull * 1024 * 2);
  f16* Vth = (f16*)alloc(1024ull * 8192 * 2);
  f16* AOh = (f16*)alloc(8192ull * 1024 * 2);
  if (ws_size < off) return;  // workspace too small: fail loudly at validation

  pack_all_kernel<<<13312, 256, 0, stream>>>(
      (const float4*)x, (const float4*)Wq, (const float4*)Wk, (const float4*)Wv,
      (const float4*)Wo, relk, relv, xh, Wqh, Wkh, Wvh, Woh, relKh, relVTh);

  // Q, K projections + V^T in one 1536-block launch (3 exact residency rounds)
  gemm_in3<<<1536, 256, 0, stream>>>(xh, Wqh, Wkh, Wvh, bq, bk, bv, Qh, Kh, Vth);

  attn_kernel<<<1024, 256, 0, stream>>>(Qh, Kh, Vth, relKh, relVTh, AOh);

  gemm_out<<<dim3(8, 64), 256, 0, stream>>>(AOh, Woh, bo, out);
}

// Round 15
// 280.185 us; speedup vs baseline: 1.0678x; 1.0678x over previous
//
#include <hip/hip_runtime.h>

typedef _Float16 f16;
typedef _Float16 f16x2 __attribute__((ext_vector_type(2)));
typedef _Float16 f16x4 __attribute__((ext_vector_type(4)));
typedef _Float16 f16x8 __attribute__((ext_vector_type(8)));
typedef float f32x4 __attribute__((ext_vector_type(4)));

static __device__ __forceinline__ f32x4 mfma16(f16x8 a, f16x8 b, f32x4 c) {
  return __builtin_amdgcn_mfma_f32_16x16x32_f16(a, b, c, 0, 0, 0);
}

// direct global->LDS, 16B per lane; LDS dest = wave-uniform base + lane*16
#define GL16(GP, LP)                                                         \
  __builtin_amdgcn_global_load_lds(                                          \
      (const __attribute__((address_space(1))) void*)(GP),                   \
      (__attribute__((address_space(3))) void*)(LP), 16, 0, 0)

// ---------------- pack kernels ----------------
// one launch for x + 4 weights, float4 -> f16x4 vectorized
__global__ void pack5_kernel(const float4* __restrict__ x, const float4* __restrict__ wq,
                             const float4* __restrict__ wk, const float4* __restrict__ wv,
                             const float4* __restrict__ wo, f16* __restrict__ xh,
                             f16* __restrict__ wqh, f16* __restrict__ wkh,
                             f16* __restrict__ wvh, f16* __restrict__ woh) {
  int i = blockIdx.x * 256 + threadIdx.x;  // 3,145,728 float4 total
  const float4* s;
  f16* d;
  int off;
  if (i < 2097152) {
    s = x;
    d = xh;
    off = i;
  } else {
    int j = i - 2097152;
    int seg = j >> 18;
    off = j & 262143;
    s = seg == 0 ? wq : seg == 1 ? wk : seg == 2 ? wv : wo;
    d = seg == 0 ? wqh : seg == 1 ? wkh : seg == 2 ? wvh : woh;
  }
  float4 v = s[off];
  f16x4 o = {(f16)v.x, (f16)v.y, (f16)v.z, (f16)v.w};
  *(f16x4*)&d[off * 4] = o;
}

// relK pad (row 2047 -> 0) and relVT transpose-pad in one launch
__global__ void packrel_kernel(const float* __restrict__ relk,
                               const float* __restrict__ relv,
                               f16* __restrict__ relKh, f16* __restrict__ relVTh) {
  int idx = blockIdx.x * 256 + threadIdx.x;  // 262144
  if (idx < 131072) {
    relKh[idx] = (idx < 2047 * 64) ? (f16)relk[idx] : (f16)0.f;
  } else {
    int k = idx - 131072;
    int dd = k >> 11, p = k & 2047;
    relVTh[k] = (p < 2047) ? (f16)relv[p * 64 + dd] : (f16)0.f;
  }
}

// ---------------- generic B^T GEMM: C[i,j] = (sum_k A[i,k]*B[j,k] + bias)*oscale ----
// 128x128, 4 waves, 2 blocks/CU (best measured geometry). 2-phase
// pipeline: double-buffered LDS, next tile's global_load_lds issued BEFORE
// compute, counted vmcnt(8) across the raw s_barrier. XOR-swizzled unpadded
// tiles. blockIdx.z selects among two (B, bias, C, oscale) sets so the
// Q and K projections run as one launch.
template <int OUT_F32, int BIAS_ROW>
__global__ __launch_bounds__(256, 2) void gemm_bt(
    const f16* __restrict__ A, const f16* __restrict__ Bp0, const f16* __restrict__ Bp1,
    const float* __restrict__ bias0, const float* __restrict__ bias1,
    void* __restrict__ C0, void* __restrict__ C1,
    int M, int N, int Kd, float osc0, float osc1) {
  const f16* B = blockIdx.z ? Bp1 : Bp0;
  const float* bias = blockIdx.z ? bias1 : bias0;
  void* Cout = blockIdx.z ? C1 : C0;
  const float oscale = blockIdx.z ? osc1 : osc0;

  __shared__ __align__(16) f16 Al[2 * 128 * 64];
  __shared__ __align__(16) f16 Bl[2 * 128 * 64];
  const int tid = threadIdx.x;
  const int w = tid >> 6, lane = tid & 63;
  const int l15 = lane & 15, hi = lane >> 4;
  const long i0 = (long)blockIdx.y * 128, j0 = (long)blockIdx.x * 128;
  const int wr = (w >> 1) * 64, wc = (w & 1) * 64;
  const int sx = (l15 & 7) * 8;  // read-side XOR swizzle (f16 units)

  // staging source (per-lane, inverse-swizzled); each GL16 line = 32 rows
  const int row_in = lane >> 3, c_lds = lane & 7;
  const int cg8 = (c_lds ^ row_in) * 8;
  const f16* agl = A + (i0 + w * 8 + row_in) * Kd + cg8;
  const f16* bgl = B + (j0 + w * 8 + row_in) * Kd + cg8;
  const int lbase = (w * 8) * 64;

#define GSTAGE(BUF, K0)                                          \
  do {                                                           \
    f16* al = Al + (BUF) * 8192 + lbase;                         \
    f16* bl = Bl + (BUF) * 8192 + lbase;                         \
    GL16(agl + (K0), al);                                        \
    GL16(agl + 32l * Kd + (K0), al + 32 * 64);                   \
    GL16(agl + 64l * Kd + (K0), al + 64 * 64);                   \
    GL16(agl + 96l * Kd + (K0), al + 96 * 64);                   \
    GL16(bgl + (K0), bl);                                        \
    GL16(bgl + 32l * Kd + (K0), bl + 32 * 64);                   \
    GL16(bgl + 64l * Kd + (K0), bl + 64 * 64);                   \
    GL16(bgl + 96l * Kd + (K0), bl + 96 * 64);                   \
  } while (0)

  f32x4 acc[4][4];
#pragma unroll
  for (int a = 0; a < 4; a++)
#pragma unroll
    for (int b2 = 0; b2 < 4; b2++) acc[a][b2] = (f32x4){0.f, 0.f, 0.f, 0.f};

  GSTAGE(0, 0);
  int cur = 0;
  for (int k0 = 0; k0 < Kd; k0 += 64) {
    if (k0 + 64 < Kd) {
      GSTAGE(cur ^ 1, k0 + 64);  // prefetch next tile into other buffer
      asm volatile("s_waitcnt vmcnt(8)" ::: "memory");  // cur tile landed
    } else {
      asm volatile("s_waitcnt vmcnt(0)" ::: "memory");
    }
    __builtin_amdgcn_s_barrier();
    __builtin_amdgcn_sched_barrier(0);
    const f16* Ac = Al + cur * 8192;
    const f16* Bc = Bl + cur * 8192;
#pragma unroll
    for (int ks = 0; ks < 2; ks++) {
      f16x8 af[4], bf[4];
#pragma unroll
      for (int mb = 0; mb < 4; mb++)
        af[mb] = *(const f16x8*)&Ac[(wr + mb * 16 + l15) * 64 + ((ks * 32 + hi * 8) ^ sx)];
#pragma unroll
      for (int nb = 0; nb < 4; nb++)
        bf[nb] = *(const f16x8*)&Bc[(wc + nb * 16 + l15) * 64 + ((ks * 32 + hi * 8) ^ sx)];
#pragma unroll
      for (int mb = 0; mb < 4; mb++)
#pragma unroll
        for (int nb = 0; nb < 4; nb++) acc[mb][nb] = mfma16(af[mb], bf[nb], acc[mb][nb]);
    }
    asm volatile("s_waitcnt lgkmcnt(0)" ::: "memory");  // reads done before swap
    __builtin_amdgcn_s_barrier();
    cur ^= 1;
  }
#undef GSTAGE
#pragma unroll
  for (int mb = 0; mb < 4; mb++) {
#pragma unroll
    for (int nb = 0; nb < 4; nb++) {
      long row = i0 + wr + mb * 16 + hi * 4;
      long col = j0 + wc + nb * 16 + l15;
      float bc = BIAS_ROW ? 0.f : bias[col];
#pragma unroll
      for (int i = 0; i < 4; i++) {
        float v = acc[mb][nb][i] + (BIAS_ROW ? bias[row + i] : bc);
        v *= oscale;
        if (OUT_F32)
          ((float*)Cout)[(row + i) * N + col] = v;
        else
          ((f16*)Cout)[(row + i) * N + col] = (f16)v;
      }
    }
  }
}

// ---------------- fused relative-position flash attention ----------------
// BM=128 per block (4 waves x 32 rows). Staging via global_load_lds (16B)
// into XOR-chunk-swizzled unpadded tiles; split drain (K/RK first, vmcnt(8)).
// P buffers (padded, ds_write scatter) alias K+RK+gap.
// Diagonal gather: source-side chunk pre-select, pack g-pair, one bpermute
// serves both groups (16 bpermutes/iter).
// grid 1024 = 8 qtiles x 128 bh, XCD-swizzled. LDS 77,824 B -> 2 blocks/CU.
__global__ __launch_bounds__(256, 2) void attn_kernel(
    const f16* __restrict__ Qh, const f16* __restrict__ Kh,
    const f16* __restrict__ Vth, const f16* __restrict__ relKh,
    const f16* __restrict__ relVTh, f16* __restrict__ AO) {
  // unified LDS, 38,912 f16 = 77,824 B
  __shared__ __align__(16) f16 SH[38912];
  f16* const ldsK = SH;            // [64][64]   staging
  f16* const ldsRK = SH + 4096;    // [192][64]  staging
  f16* const ldsP = SH;            // [128][72]  alias: Pmain (after B2)
  f16* const ldsPS = SH + 9216;    // [128][104] alias+gap: Pskew (after B2)
  f16* const ldsV = SH + 22528;    // [64][64]
  f16* const ldsRV = SH + 26624;   // [64][192]

  const int tid = threadIdx.x;
  const int w = tid >> 6, lane = tid & 63;
  const int l15 = lane & 15, hi = lane >> 4;
  // XCD swizzle: 8 q-tiles of one (b,h) consecutive on one XCD
  const int flat = blockIdx.x;
  const int xcd = flat & 7, slot = flat >> 3;
  const int bh = xcd * 16 + (slot >> 3);
  const int qt = slot & 7;
  const int b = bh >> 4, h = bh & 15;
  const int l0 = qt * 128;
  const int cu = 6 - 2 * w;      // RK union chunk base (6 chunks)
  const int rvco = 96 - 32 * w;  // PV-rel B-col base in RV band
  const int sx = (l15 & 7) * 8;  // read-side XOR swizzle (f16 units)

  // ---- global_load_lds source pointers (per-lane, inverse-swizzled) ----
  const int row_in = lane >> 3;   // 0..7
  const int c_lds = lane & 7;
  const int cg8 = (c_lds ^ row_in) * 8;
  const f16* kgl = Kh + ((long)(b * 1024 + w * 16 + row_in)) * 1024 + h * 64 + cg8;
  const f16* vgl = Vth + ((long)(h * 64 + w * 16 + row_in)) * 8192 + b * 1024 + cg8;
  const f16* rkgl = relKh + (long)(896 - l0 + w * 48 + row_in) * 64 + cg8;
  // RV flat: issue q covers flat 16B-chunks f = (w*6+q)*64 + lane;
  // row = f/24, c = f%24, source chunk = c ^ (row&7)
#define RVP(Q)                                                                   \
  (relVTh + (long)(((w * 6 + (Q)) * 64 + lane) / 24) * 2048 + (896 - l0) +       \
   ((((w * 6 + (Q)) * 64 + lane) % 24) ^ ((((w * 6 + (Q)) * 64 + lane) / 24) & 7)) * 8)
  const f16* rvg0 = RVP(0);
  const f16* rvg1 = RVP(1);
  const f16* rvg2 = RVP(2);
  const f16* rvg3 = RVP(3);
  const f16* rvg4 = RVP(4);
  const f16* rvg5 = RVP(5);
#undef RVP

  // Q fragments: rows l0 + 32w + 16g + l15, k-halves ks
  const long qbase = ((long)(b * 1024 + l0 + w * 32 + l15)) * 1024 + h * 64 + hi * 8;
  const f16x8 qf00 = *(const f16x8*)(Qh + qbase);
  const f16x8 qf01 = *(const f16x8*)(Qh + qbase + 32);
  const f16x8 qf10 = *(const f16x8*)(Qh + qbase + 16l * 1024);
  const f16x8 qf11 = *(const f16x8*)(Qh + qbase + 16l * 1024 + 32);

  const f16x8 ones1 = {(f16)1.f, (f16)1.f, (f16)1.f, (f16)1.f,
                       (f16)1.f, (f16)1.f, (f16)1.f, (f16)1.f};

  f32x4 acc_o[2][4];
#pragma unroll
  for (int g = 0; g < 2; g++)
#pragma unroll
    for (int cf = 0; cf < 4; cf++) acc_o[g][cf] = (f32x4){0.f, 0.f, 0.f, 0.f};
  float mrow[2][4], lsum[2][4];
#pragma unroll
  for (int g = 0; g < 2; g++)
#pragma unroll
    for (int i = 0; i < 4; i++) {
      mrow[g][i] = -1e30f;
      lsum[g][i] = 0.f;
    }

  for (int kt = 0; kt < 16; kt++) {
    const int r0 = kt * 64;
    __syncthreads();  // B0: all PV + P-alias reads of prev iter done
    {
      // K/RK first (8 lines) -- needed at B1 for QK
      const long ko = (long)r0 * 1024;
      GL16(kgl + ko, ldsK + (w * 16) * 64);
      GL16(kgl + ko + 8 * 1024, ldsK + (w * 16 + 8) * 64);
      const int rko = r0 * 64;
      GL16(rkgl + rko, ldsRK + (w * 48) * 64);
      GL16(rkgl + rko + 512, ldsRK + (w * 48 + 8) * 64);
      GL16(rkgl + rko + 1024, ldsRK + (w * 48 + 16) * 64);
      GL16(rkgl + rko + 1536, ldsRK + (w * 48 + 24) * 64);
      GL16(rkgl + rko + 2048, ldsRK + (w * 48 + 32) * 64);
      GL16(rkgl + rko + 2560, ldsRK + (w * 48 + 40) * 64);
      // V/RV last (8 lines) -- only needed by PV (guaranteed by B2 drain)
      GL16(vgl + r0, ldsV + (w * 16) * 64);
      GL16(vgl + r0 + 8l * 8192, ldsV + (w * 16 + 8) * 64);
      GL16(rvg0 + r0, ldsRV + (w * 6 + 0) * 512);
      GL16(rvg1 + r0, ldsRV + (w * 6 + 1) * 512);
      GL16(rvg2 + r0, ldsRV + (w * 6 + 2) * 512);
      GL16(rvg3 + r0, ldsRV + (w * 6 + 3) * 512);
      GL16(rvg4 + r0, ldsRV + (w * 6 + 4) * 512);
      GL16(rvg5 + r0, ldsRV + (w * 6 + 5) * 512);
    }
    // B1 split drain: wait only for own K/RK (first 8), barrier, pin order.
    asm volatile("s_waitcnt vmcnt(8)" ::: "memory");
    __builtin_amdgcn_s_barrier();
    __builtin_amdgcn_sched_barrier(0);

    // QK: S = Q*(K/8)^T per group; QR = Q·relK over 5 chunks/group
    f32x4 sacc[2][4], qracc[2][5];
#pragma unroll
    for (int g = 0; g < 2; g++) {
#pragma unroll
      for (int cf = 0; cf < 4; cf++) sacc[g][cf] = (f32x4){0.f, 0.f, 0.f, 0.f};
#pragma unroll
      for (int j = 0; j < 5; j++) qracc[g][j] = (f32x4){0.f, 0.f, 0.f, 0.f};
    }
    __builtin_amdgcn_s_setprio(1);
#pragma unroll
    for (int ks = 0; ks < 2; ks++) {
      f16x8 kf[4], rf[6];
#pragma unroll
      for (int cf = 0; cf < 4; cf++)
        kf[cf] = *(const f16x8*)&ldsK[(cf * 16 + l15) * 64 + ((ks * 32 + hi * 8) ^ sx)];
#pragma unroll
      for (int j = 0; j < 6; j++)
        rf[j] =
            *(const f16x8*)&ldsRK[((cu + j) * 16 + l15) * 64 + ((ks * 32 + hi * 8) ^ sx)];
      f16x8 q0 = ks ? qf01 : qf00;
      f16x8 q1 = ks ? qf11 : qf10;
#pragma unroll
      for (int cf = 0; cf < 4; cf++) {
        sacc[0][cf] = mfma16(q0, kf[cf], sacc[0][cf]);
        sacc[1][cf] = mfma16(q1, kf[cf], sacc[1][cf]);
      }
#pragma unroll
      for (int j = 0; j < 5; j++) {
        qracc[0][j] = mfma16(q0, rf[j + 1], qracc[0][j]);
        qracc[1][j] = mfma16(q1, rf[j], qracc[1][j]);
      }
    }
    __builtin_amdgcn_s_setprio(0);
    __syncthreads();  // B2: QK reads done (+full vmcnt drain: V/RV landed)

    // in-register diagonal gather, source-side pre-select:
    // src lane (pos p=l15 in its 16-lane group) serves exactly one consumer;
    // that consumer's wrap = (p + hi*4 + i <= 14). Pre-select chunk cf/cf+1
    // on the source, pack the g-pair, one bpermute serves both groups.
#pragma unroll
    for (int i = 0; i < 4; i++) {
      int t = 15 + l15 - (hi * 4 + i);
      int idx = (hi * 16 + (t & 15)) * 4;
      bool wrapc = (l15 + hi * 4 + i) <= 14;  // consumer-of-this-src wrap
#pragma unroll
      for (int cf = 0; cf < 4; cf++) {
        float s0 = wrapc ? qracc[0][cf + 1][i] : qracc[0][cf][i];
        float s1 = wrapc ? qracc[1][cf + 1][i] : qracc[1][cf][i];
        auto pkv = __builtin_amdgcn_cvt_pkrtz(s0, s1);
        int gg = __builtin_amdgcn_ds_bpermute(idx, __builtin_bit_cast(int, pkv));
        f16x2 two = __builtin_bit_cast(f16x2, gg);
        sacc[0][cf][i] += (float)two[0];
        sacc[1][cf][i] += (float)two[1];
      }
    }

    // online softmax per group
    float rmax[2][4];
#pragma unroll
    for (int g = 0; g < 2; g++)
#pragma unroll
      for (int i = 0; i < 4; i++)
        rmax[g][i] = fmaxf(fmaxf(sacc[g][0][i], sacc[g][1][i]),
                           fmaxf(sacc[g][2][i], sacc[g][3][i]));
#pragma unroll
    for (int m = 1; m < 16; m <<= 1)
#pragma unroll
      for (int g = 0; g < 2; g++)
#pragma unroll
        for (int i = 0; i < 4; i++)
          rmax[g][i] = fmaxf(rmax[g][i], __shfl_xor(rmax[g][i], m, 64));
    {
      bool big = false;
#pragma unroll
      for (int g = 0; g < 2; g++)
#pragma unroll
        for (int i = 0; i < 4; i++) big |= rmax[g][i] > mrow[g][i] + 8.f;
      if (__any(big)) {
#pragma unroll
        for (int g = 0; g < 2; g++)
#pragma unroll
          for (int i = 0; i < 4; i++) {
            float mn = fmaxf(mrow[g][i], rmax[g][i]);
            float al = __expf(mrow[g][i] - mn);
            mrow[g][i] = mn;
            lsum[g][i] *= al;
#pragma unroll
            for (int cf = 0; cf < 4; cf++) acc_o[g][cf][i] *= al;
          }
      }
    }
#pragma unroll
    for (int g = 0; g < 2; g++)
#pragma unroll
      for (int cf = 0; cf < 4; cf++)
#pragma unroll
        for (int i = 0; i < 4; i++)
          sacc[g][cf][i] = __expf(sacc[g][cf][i] - mrow[g][i]);  // P (<= e^8)

    // zero own PS rows' window [0,96), then scatter P
    const uint4 z4 = make_uint4(0u, 0u, 0u, 0u);
#pragma unroll
    for (int r2 = 0; r2 < 2; r2++)
#pragma unroll
      for (int s = 0; s < 3; s++)
        *(uint4*)&ldsPS[(w * 32 + r2 * 16 + (lane >> 2)) * 104 + (lane & 3) * 8 + 32 * s] =
            z4;
#pragma unroll
    for (int g = 0; g < 2; g++)
#pragma unroll
      for (int cf = 0; cf < 4; cf++)
#pragma unroll
        for (int i = 0; i < 4; i++) {
          int rr = 16 * g + hi * 4 + i;  // local row in wave [0,32)
          int ri = cf * 16 + l15;
          f16 ph = (f16)sacc[g][cf][i];
          ldsP[(w * 32 + rr) * 72 + ri] = ph;
          ldsPS[(w * 32 + rr) * 104 + 31 + ri - rr] = ph;  // col'' = 31+ri-rr
        }
    // DS pipe is in-order per wave: PV reads below see the scatter writes.
    __builtin_amdgcn_sched_barrier(0);

    __builtin_amdgcn_s_setprio(1);
    // O += P @ V ; row-sums via ones-MFMA on the same pa fragments
    f32x4 rs0 = (f32x4){0.f, 0.f, 0.f, 0.f}, rs1 = (f32x4){0.f, 0.f, 0.f, 0.f};
#pragma unroll
    for (int ks = 0; ks < 2; ks++) {
      f16x8 pa0 = *(const f16x8*)&ldsP[(w * 32 + l15) * 72 + ks * 32 + hi * 8];
      f16x8 pa1 = *(const f16x8*)&ldsP[(w * 32 + 16 + l15) * 72 + ks * 32 + hi * 8];
      rs0 = mfma16(pa0, ones1, rs0);
      rs1 = mfma16(pa1, ones1, rs1);
#pragma unroll
      for (int cf = 0; cf < 4; cf++) {
        f16x8 vb = *(const f16x8*)&ldsV[(cf * 16 + l15) * 64 + ((ks * 32 + hi * 8) ^ sx)];
        acc_o[0][cf] = mfma16(pa0, vb, acc_o[0][cf]);
        acc_o[1][cf] = mfma16(pa1, vb, acc_o[1][cf]);
      }
    }
    // O += Pskew @ relV_band (3 ks chunks, B-col base rvco = 96-32w)
#pragma unroll
    for (int ks = 0; ks < 3; ks++) {
      f16x8 ps0 = *(const f16x8*)&ldsPS[(w * 32 + l15) * 104 + ks * 32 + hi * 8];
      f16x8 ps1 = *(const f16x8*)&ldsPS[(w * 32 + 16 + l15) * 104 + ks * 32 + hi * 8];
#pragma unroll
      for (int cf = 0; cf < 4; cf++) {
        f16x8 rb = *(const f16x8*)&ldsRV[(cf * 16 + l15) * 192 +
                                         ((rvco + ks * 32 + hi * 8) ^ sx)];
        acc_o[0][cf] = mfma16(ps0, rb, acc_o[0][cf]);
        acc_o[1][cf] = mfma16(ps1, rb, acc_o[1][cf]);
      }
    }
    __builtin_amdgcn_s_setprio(0);
#pragma unroll
    for (int i = 0; i < 4; i++) {
      lsum[0][i] += rs0[i];
      lsum[1][i] += rs1[i];
    }
  }
  // epilogue: normalize, store fp16 to AO[b*1024+l][h*64+d]
#pragma unroll
  for (int g = 0; g < 2; g++)
#pragma unroll
    for (int cf = 0; cf < 4; cf++)
#pragma unroll
      for (int i = 0; i < 4; i++) {
        float v = acc_o[g][cf][i] / lsum[g][i];
        AO[((long)(b * 1024 + l0 + w * 32 + 16 * g + hi * 4 + i)) * 1024 + h * 64 +
           cf * 16 + l15] = (f16)v;
      }
}

// ---------------- launch ----------------
extern "C" void kernel_launch(void* const* d_in, const int* in_sizes, int n_in,
                              void* d_out, int out_size, void* d_ws, size_t ws_size,
                              hipStream_t stream) {
  const float* x = (const float*)d_in[0];
  const float* Wq = (const float*)d_in[1];
  const float* bq = (const float*)d_in[2];
  const float* Wk = (const float*)d_in[3];
  const float* bk = (const float*)d_in[4];
  const float* Wv = (const float*)d_in[5];
  const float* bv = (const float*)d_in[6];
  const float* Wo = (const float*)d_in[7];
  const float* bo = (const float*)d_in[8];
  const float* relk = (const float*)d_in[9];
  const float* relv = (const float*)d_in[10];
  float* out = (float*)d_out;

  char* ws = (char*)d_ws;
  size_t off = 0;
  auto alloc = [&](size_t bytes) {
    char* p = ws + off;
    off += (bytes + 255) & ~(size_t)255;
    return p;
  };
  f16* xh = (f16*)alloc(8192ull * 1024 * 2);
  f16* Wqh = (f16*)alloc(1024ull * 1024 * 2);
  f16* Wkh = (f16*)alloc(1024ull * 1024 * 2);
  f16* Wvh = (f16*)alloc(1024ull * 1024 * 2);
  f16* Woh = (f16*)alloc(1024ull * 1024 * 2);
  f16* relKh = (f16*)alloc(2048ull * 64 * 2);
  f16* relVTh = (f16*)alloc(64ull * 2048 * 2);
  f16* Qh = (f16*)alloc(8192ull * 1024 * 2);
  f16* Kh = (f16*)alloc(8192ull * 1024 * 2);
  f16* Vth = (f16*)alloc(1024ull * 8192 * 2);
  f16* AOh = (f16*)alloc(8192ull * 1024 * 2);
  if (ws_size < off) return;  // workspace too small: fail loudly at validation

  pack5_kernel<<<12288, 256, 0, stream>>>((const float4*)x, (const float4*)Wq,
                                          (const float4*)Wk, (const float4*)Wv,
                                          (const float4*)Wo, xh, Wqh, Wkh, Wvh, Woh);
  packrel_kernel<<<1024, 256, 0, stream>>>(relk, relv, relKh, relVTh);

  // Q and K projections fused via blockIdx.z
  gemm_bt<0, 0><<<dim3(8, 64, 2), 256, 0, stream>>>(
      xh, Wqh, Wkh, bq, bk, Qh, Kh, 8192, 1024, 1024, 1.0f, 0.125f);
  // V^T = Wv @ x^T : M=1024, N=8192
  gemm_bt<0, 1><<<dim3(64, 8, 1), 256, 0, stream>>>(
      Wvh, xh, xh, bv, bv, Vth, Vth, 1024, 8192, 1024, 1.0f, 1.0f);

  attn_kernel<<<1024, 256, 0, stream>>>(Qh, Kh, Vth, relKh, relVTh, AOh);

  gemm_bt<1, 0><<<dim3(8, 64, 1), 256, 0, stream>>>(
      AOh, Woh, Woh, bo, bo, out, out, 8192, 1024, 1024, 1.0f, 1.0f);
}